// Round 2
// baseline (432.669 us; speedup 1.0000x reference)
//
#include <hip/hip_runtime.h>

// R2: prep kernel converts K/V (cache++new merged) to bf16 in d_ws, laid out in
// MFMA fragment order per 32-key tile. Hot kernel loads fragments directly from
// global (L1/L2-resident), no K/V LDS staging, no barriers in the K-loop.
// Fallback to R1 kernel if ws_size too small.

#define BB 4
#define QQ 1024
#define SS 2048
#define HH 32
#define DD 128
#define QT 64
#define KT 32
#define NTILES 64          // SS/KT
#define TILE_ELEMS 4096    // KT*DD
#define PST 40
#define VST 40

typedef __attribute__((ext_vector_type(8))) short short8;
typedef __attribute__((ext_vector_type(4))) float f32x4;
typedef __attribute__((ext_vector_type(4))) unsigned short u16x4;
typedef __attribute__((ext_vector_type(8))) unsigned short u16x8;

__device__ __forceinline__ unsigned short f2bf(float f) {
    unsigned int u = __builtin_bit_cast(unsigned int, f);
    u += 0x7FFFu + ((u >> 16) & 1u);
    return (unsigned short)(u >> 16);
}

// ---------------- prep: f32 cache/new -> bf16 fragment-ordered ws ----------------
__global__ __launch_bounds__(256)
void prep(const float* __restrict__ ks, const float* __restrict__ vs,
          const float* __restrict__ kc, const float* __restrict__ vc,
          const int* __restrict__ qlens, const int* __restrict__ clens,
          unsigned short* __restrict__ Kws, unsigned short* __restrict__ Vws)
{
    const int tile = blockIdx.x, h = blockIdx.y, b = blockIdx.z;
    const int qlen = qlens[b], clen = clens[b];
    if (tile * KT >= clen + qlen) return;
    const int tid = threadIdx.x;
    unsigned short* kout = Kws + (((size_t)b * HH + h) * NTILES + tile) * TILE_ELEMS;
    unsigned short* vout = Vws + (((size_t)b * HH + h) * NTILES + tile) * TILE_ELEMS;

    // K: fragment order off = half*2048 + c*512 + key15*32 + g*8 + e
    #pragma unroll
    for (int half = 0; half < 2; ++half) {
        int idx = tid * 8;
        int c = (idx >> 9) & 3, key15 = (idx >> 5) & 15, g = (idx >> 3) & 3;
        int key = tile * KT + half * 16 + key15;
        const float* src;
        if (key < clen) {
            src = kc + (((size_t)b * SS + key) * HH + h) * DD;
        } else {
            int i2 = key - clen; if (i2 > QQ - 1) i2 = QQ - 1;
            src = ks + (((size_t)b * QQ + i2) * HH + h) * DD;
        }
        int d0 = c * 32 + g * 8;
        f32x4 a0 = *(const f32x4*)&src[d0];
        f32x4 a1 = *(const f32x4*)&src[d0 + 4];
        u16x8 w;
        w[0] = f2bf(a0[0]); w[1] = f2bf(a0[1]); w[2] = f2bf(a0[2]); w[3] = f2bf(a0[3]);
        w[4] = f2bf(a1[0]); w[5] = f2bf(a1[1]); w[6] = f2bf(a1[2]); w[7] = f2bf(a1[3]);
        *(u16x8*)&kout[half * 2048 + idx] = w;
    }
    // V^T: fragment order off = n*512 + lc*32 + g*8 + e  (value = V[key=g*8+e][d=n*16+lc])
    #pragma unroll
    for (int it = 0; it < 2; ++it) {
        int idx = it * 2048 + tid * 8;
        int n = (idx >> 9) & 7, lc = (idx >> 5) & 15, g = (idx >> 3) & 3;
        int d = n * 16 + lc;
        u16x8 w;
        #pragma unroll
        for (int e = 0; e < 8; ++e) {
            int key = tile * KT + g * 8 + e;
            const float* src;
            if (key < clen) {
                src = vc + (((size_t)b * SS + key) * HH + h) * DD;
            } else {
                int i2 = key - clen; if (i2 > QQ - 1) i2 = QQ - 1;
                src = vs + (((size_t)b * QQ + i2) * HH + h) * DD;
            }
            w[e] = f2bf(src[d]);
        }
        *(u16x8*)&vout[idx] = w;
    }
}

// ---------------- hot: fragment loads from ws, no K/V LDS ----------------
__global__ __launch_bounds__(256)
void segattn_fast(const float* __restrict__ qs, const int* __restrict__ qlens,
                  const int* __restrict__ clens,
                  const unsigned short* __restrict__ Kws,
                  const unsigned short* __restrict__ Vws,
                  float* __restrict__ out)
{
    const int id = blockIdx.x;
    const int id2 = (id & 7) * 256 + (id >> 3);      // XCD-chunked swizzle (2048%8==0)
    const int qt = id2 & 15, hb = id2 >> 4, h = hb & 31, b = hb >> 5;
    const int tid = threadIdx.x, wave = tid >> 6, lane = tid & 63;
    const int g = lane >> 4, lc = lane & 15;
    const int qlen = qlens[b], clen = clens[b];
    const int q0 = qt * QT;

    if (q0 >= qlen) {
        f32x4 z = {0.f, 0.f, 0.f, 0.f};
        #pragma unroll
        for (int i2 = 0; i2 < 8; ++i2) {
            int f = tid + i2 * 256;
            int r = f >> 5, d4 = f & 31;
            *(f32x4*)&out[(((size_t)b * QQ + q0 + r) * HH + h) * DD + d4 * 4] = z;
        }
        return;
    }

    alignas(16) __shared__ unsigned short Pl[4][16][PST];

    const float psc = 0.08838834764831845f * 1.4426950408889634f;
    const int qrow = q0 + wave * 16 + lc;
    const float* qp = qs + (((size_t)b * QQ + qrow) * HH + h) * DD;
    short8 qf[4];
    #pragma unroll
    for (int c = 0; c < 4; ++c) {
        f32x4 a0 = *(const f32x4*)&qp[c * 32 + g * 8];
        f32x4 a1 = *(const f32x4*)&qp[c * 32 + g * 8 + 4];
        short8 t;
        t[0] = (short)f2bf(a0[0] * psc); t[1] = (short)f2bf(a0[1] * psc);
        t[2] = (short)f2bf(a0[2] * psc); t[3] = (short)f2bf(a0[3] * psc);
        t[4] = (short)f2bf(a1[0] * psc); t[5] = (short)f2bf(a1[1] * psc);
        t[6] = (short)f2bf(a1[2] * psc); t[7] = (short)f2bf(a1[3] * psc);
        qf[c] = t;
    }

    f32x4 o[8];
    #pragma unroll
    for (int n = 0; n < 8; ++n) o[n] = (f32x4){0.f, 0.f, 0.f, 0.f};
    float m_[4] = {-3e38f, -3e38f, -3e38f, -3e38f};
    float l_[4] = {0.f, 0.f, 0.f, 0.f};

    int lim[4];
    #pragma unroll
    for (int qq = 0; qq < 4; ++qq) {
        int i = q0 + wave * 16 + g * 4 + qq;
        lim[qq] = (i < qlen) ? (clen + i + 1) : 0;
    }

    const int kmax = clen + min(q0 + QT, qlen);
    const int nt = (kmax + KT - 1) / KT;

    const unsigned short* Kb = Kws + ((size_t)(b * HH + h)) * NTILES * TILE_ELEMS;
    const unsigned short* Vb = Vws + ((size_t)(b * HH + h)) * NTILES * TILE_ELEMS;
    const int fo = lc * 32 + g * 8;   // per-lane fragment offset

    for (int t = 0; t < nt; ++t) {
        const int pbase = t * KT;
        const unsigned short* kt_ = Kb + (size_t)t * TILE_ELEMS;
        const unsigned short* vt_ = Vb + (size_t)t * TILE_ELEMS;

        f32x4 sc0 = {0.f, 0.f, 0.f, 0.f}, sc1 = {0.f, 0.f, 0.f, 0.f};
        #pragma unroll
        for (int c = 0; c < 4; ++c) {
            short8 k0 = *(const short8*)&kt_[c * 512 + fo];
            short8 k1 = *(const short8*)&kt_[2048 + c * 512 + fo];
            sc0 = __builtin_amdgcn_mfma_f32_16x16x32_bf16(qf[c], k0, sc0, 0, 0, 0);
            sc1 = __builtin_amdgcn_mfma_f32_16x16x32_bf16(qf[c], k1, sc1, 0, 0, 0);
        }

        // issue V fragment loads early (independent of softmax)
        short8 vf[8];
        #pragma unroll
        for (int n = 0; n < 8; ++n) vf[n] = *(const short8*)&vt_[n * 512 + fo];

        float pr0[4], pr1[4];
        #pragma unroll
        for (int qq = 0; qq < 4; ++qq) {
            float s0 = sc0[qq], s1 = sc1[qq];
            if (pbase + lc >= lim[qq])      s0 = -3e38f;
            if (pbase + 16 + lc >= lim[qq]) s1 = -3e38f;
            float pm = fmaxf(s0, s1);
            #pragma unroll
            for (int d2 = 1; d2 < 16; d2 <<= 1) pm = fmaxf(pm, __shfl_xor(pm, d2));
            float mn = fmaxf(m_[qq], pm);
            float alpha = exp2f(m_[qq] - mn);
            float p0 = exp2f(s0 - mn), p1 = exp2f(s1 - mn);
            float rs = p0 + p1;
            #pragma unroll
            for (int d2 = 1; d2 < 16; d2 <<= 1) rs += __shfl_xor(rs, d2);
            l_[qq] = l_[qq] * alpha + rs;
            m_[qq] = mn;
            pr0[qq] = p0; pr1[qq] = p1;
            #pragma unroll
            for (int n = 0; n < 8; ++n) o[n][qq] *= alpha;
        }

        #pragma unroll
        for (int qq = 0; qq < 4; ++qq) {
            Pl[wave][g * 4 + qq][lc]      = f2bf(pr0[qq]);
            Pl[wave][g * 4 + qq][16 + lc] = f2bf(pr1[qq]);
        }
        short8 pf = *(const short8*)&Pl[wave][lc][g * 8];
        #pragma unroll
        for (int n = 0; n < 8; ++n)
            o[n] = __builtin_amdgcn_mfma_f32_16x16x32_bf16(pf, vf[n], o[n], 0, 0, 0);
    }

    #pragma unroll
    for (int qq = 0; qq < 4; ++qq) {
        int i = q0 + wave * 16 + g * 4 + qq;
        bool val = (i < qlen);
        float inv = val ? (1.0f / l_[qq]) : 0.f;
        size_t ob = (((size_t)b * QQ + i) * HH + h) * DD + lc;
        #pragma unroll
        for (int n = 0; n < 8; ++n)
            out[ob + (size_t)n * 16] = val ? o[n][qq] * inv : 0.f;
    }
}

// ---------------- R1 fallback (proven) if ws too small ----------------
__global__ __launch_bounds__(256)
void segattn(const float* __restrict__ qs, const float* __restrict__ ks,
             const float* __restrict__ vs, const float* __restrict__ kc,
             const float* __restrict__ vc, const int* __restrict__ qlens,
             const int* __restrict__ clens, float* __restrict__ out)
{
    const int qt = blockIdx.x, h = blockIdx.y, b = blockIdx.z;
    const int tid = threadIdx.x, wave = tid >> 6, lane = tid & 63;
    const int g = lane >> 4, lc = lane & 15;
    const int qlen = qlens[b], clen = clens[b];
    const int q0 = qt * QT;

    if (q0 >= qlen) {
        f32x4 z = {0.f, 0.f, 0.f, 0.f};
        #pragma unroll
        for (int i2 = 0; i2 < 8; ++i2) {
            int f = tid + i2 * 256;
            int r = f >> 5, d4 = f & 31;
            *(f32x4*)&out[(((size_t)b * QQ + q0 + r) * HH + h) * DD + d4 * 4] = z;
        }
        return;
    }

    alignas(16) __shared__ unsigned short Kl[KT * DD];
    alignas(16) __shared__ unsigned short Vl[DD * VST];
    alignas(16) __shared__ unsigned short Pl[4][16][PST];

    const float psc = 0.08838834764831845f * 1.4426950408889634f;
    const int qrow = q0 + wave * 16 + lc;
    const float* qp = qs + (((size_t)b * QQ + qrow) * HH + h) * DD;
    short8 qf[4];
    #pragma unroll
    for (int c = 0; c < 4; ++c) {
        f32x4 a0 = *(const f32x4*)&qp[c * 32 + g * 8];
        f32x4 a1 = *(const f32x4*)&qp[c * 32 + g * 8 + 4];
        short8 t;
        t[0] = (short)f2bf(a0[0] * psc); t[1] = (short)f2bf(a0[1] * psc);
        t[2] = (short)f2bf(a0[2] * psc); t[3] = (short)f2bf(a0[3] * psc);
        t[4] = (short)f2bf(a1[0] * psc); t[5] = (short)f2bf(a1[1] * psc);
        t[6] = (short)f2bf(a1[2] * psc); t[7] = (short)f2bf(a1[3] * psc);
        qf[c] = t;
    }

    f32x4 o[8];
    #pragma unroll
    for (int n = 0; n < 8; ++n) o[n] = (f32x4){0.f, 0.f, 0.f, 0.f};
    float m_[4] = {-3e38f, -3e38f, -3e38f, -3e38f};
    float l_[4] = {0.f, 0.f, 0.f, 0.f};

    int lim[4];
    #pragma unroll
    for (int qq = 0; qq < 4; ++qq) {
        int i = q0 + wave * 16 + g * 4 + qq;
        lim[qq] = (i < qlen) ? (clen + i + 1) : 0;
    }

    const int kmax = clen + min(q0 + QT, qlen);
    const int nt = (kmax + KT - 1) / KT;

    for (int t = 0; t < nt; ++t) {
        const int pbase = t * KT;
        __syncthreads();
        #pragma unroll
        for (int it = 0; it < 4; ++it) {
            int f = tid + it * 256;
            int key = f >> 5, d4 = f & 31;
            int p = pbase + key;
            const float *srck, *srcv;
            if (p < clen) {
                size_t off = (((size_t)b * SS + p) * HH + h) * DD + d4 * 4;
                srck = kc + off; srcv = vc + off;
            } else {
                int idx = p - clen; if (idx > QQ - 1) idx = QQ - 1;
                size_t off = (((size_t)b * QQ + idx) * HH + h) * DD + d4 * 4;
                srck = ks + off; srcv = vs + off;
            }
            f32x4 kv = *(const f32x4*)srck;
            f32x4 vv = *(const f32x4*)srcv;
            int ei = (key * DD + d4 * 4) ^ ((key & 7) << 3);
            u16x4 kb4 = {f2bf(kv[0]), f2bf(kv[1]), f2bf(kv[2]), f2bf(kv[3])};
            *(u16x4*)&Kl[ei] = kb4;
            int d0 = d4 * 4;
            Vl[(d0 + 0) * VST + key] = f2bf(vv[0]);
            Vl[(d0 + 1) * VST + key] = f2bf(vv[1]);
            Vl[(d0 + 2) * VST + key] = f2bf(vv[2]);
            Vl[(d0 + 3) * VST + key] = f2bf(vv[3]);
        }
        __syncthreads();

        f32x4 sc0 = {0.f, 0.f, 0.f, 0.f}, sc1 = {0.f, 0.f, 0.f, 0.f};
        #pragma unroll
        for (int c = 0; c < 4; ++c) {
            int i0 = (lc * DD + c * 32 + g * 8) ^ ((lc & 7) << 3);
            int i1 = ((16 + lc) * DD + c * 32 + g * 8) ^ (((16 + lc) & 7) << 3);
            short8 k0 = *(const short8*)&Kl[i0];
            short8 k1 = *(const short8*)&Kl[i1];
            sc0 = __builtin_amdgcn_mfma_f32_16x16x32_bf16(qf[c], k0, sc0, 0, 0, 0);
            sc1 = __builtin_amdgcn_mfma_f32_16x16x32_bf16(qf[c], k1, sc1, 0, 0, 0);
        }

        float pr0[4], pr1[4];
        #pragma unroll
        for (int qq = 0; qq < 4; ++qq) {
            float s0 = sc0[qq], s1 = sc1[qq];
            if (pbase + lc >= lim[qq])      s0 = -3e38f;
            if (pbase + 16 + lc >= lim[qq]) s1 = -3e38f;
            float pm = fmaxf(s0, s1);
            #pragma unroll
            for (int d2 = 1; d2 < 16; d2 <<= 1) pm = fmaxf(pm, __shfl_xor(pm, d2));
            float mn = fmaxf(m_[qq], pm);
            float alpha = exp2f(m_[qq] - mn);
            float p0 = exp2f(s0 - mn), p1 = exp2f(s1 - mn);
            float rs = p0 + p1;
            #pragma unroll
            for (int d2 = 1; d2 < 16; d2 <<= 1) rs += __shfl_xor(rs, d2);
            l_[qq] = l_[qq] * alpha + rs;
            m_[qq] = mn;
            pr0[qq] = p0; pr1[qq] = p1;
            #pragma unroll
            for (int n = 0; n < 8; ++n) o[n][qq] *= alpha;
        }

        #pragma unroll
        for (int qq = 0; qq < 4; ++qq) {
            Pl[wave][g * 4 + qq][lc]      = f2bf(pr0[qq]);
            Pl[wave][g * 4 + qq][16 + lc] = f2bf(pr1[qq]);
        }
        short8 pf = *(const short8*)&Pl[wave][lc][g * 8];
        #pragma unroll
        for (int n = 0; n < 8; ++n) {
            short8 vf = *(const short8*)&Vl[(n * 16 + lc) * VST + g * 8];
            o[n] = __builtin_amdgcn_mfma_f32_16x16x32_bf16(pf, vf, o[n], 0, 0, 0);
        }
    }

    #pragma unroll
    for (int qq = 0; qq < 4; ++qq) {
        int i = q0 + wave * 16 + g * 4 + qq;
        bool val = (i < qlen);
        float inv = val ? (1.0f / l_[qq]) : 0.f;
        size_t ob = (((size_t)b * QQ + i) * HH + h) * DD + lc;
        #pragma unroll
        for (int n = 0; n < 8; ++n)
            out[ob + (size_t)n * 16] = val ? o[n][qq] * inv : 0.f;
    }
}

extern "C" void kernel_launch(void* const* d_in, const int* in_sizes, int n_in,
                              void* d_out, int out_size, void* d_ws, size_t ws_size,
                              hipStream_t stream) {
    const float* qs = (const float*)d_in[0];
    const float* ks = (const float*)d_in[1];
    const float* vs = (const float*)d_in[2];
    const float* kc = (const float*)d_in[3];
    const float* vc = (const float*)d_in[4];
    const int* ql = (const int*)d_in[5];
    const int* cl = (const int*)d_in[6];
    float* o = (float*)d_out;

    const size_t kv_elems = (size_t)BB * HH * NTILES * TILE_ELEMS;   // 33.55M
    const size_t need = kv_elems * 2 * sizeof(unsigned short);        // 128 MiB

    if (ws_size >= need) {
        unsigned short* Kws = (unsigned short*)d_ws;
        unsigned short* Vws = Kws + kv_elems;
        dim3 pgrid(NTILES, HH, BB), pblk(256, 1, 1);
        hipLaunchKernelGGL(prep, pgrid, pblk, 0, stream, ks, vs, kc, vc, ql, cl, Kws, Vws);
        dim3 grid(2048, 1, 1), blk(256, 1, 1);
        hipLaunchKernelGGL(segattn_fast, grid, blk, 0, stream, qs, ql, cl, Kws, Vws, o);
    } else {
        dim3 grid(QQ / QT, HH, BB), blk(256, 1, 1);
        hipLaunchKernelGGL(segattn, grid, blk, 0, stream, qs, ks, vs, kc, vc, ql, cl, o);
    }
}

// Round 3
// 233.565 us; speedup vs baseline: 1.8525x; 1.8525x over previous
//
#include <hip/hip_runtime.h>

// R3: swapped-operand QK^T (mfma(K,Q)) -> lane-local softmax (2 shfl hops),
// P relayout via 8 ds_bpermute (zero LDS), PV as V^T·P with float4 stores.
// K-fragment prefetch (1 tile deep), early V loads, balanced block swizzle.
// Prep kernel converts K/V (cache++new) to bf16 fragment-ordered ws once.

#define BB 4
#define QQ 1024
#define SS 2048
#define HH 32
#define DD 128
#define QT 64
#define KT 32
#define NTILES 64          // SS/KT
#define TILE_ELEMS 4096    // KT*DD

typedef __attribute__((ext_vector_type(8))) short short8;
typedef __attribute__((ext_vector_type(4))) float f32x4;
typedef __attribute__((ext_vector_type(4))) unsigned int u32x4;
typedef __attribute__((ext_vector_type(8))) unsigned short u16x8;

__device__ __forceinline__ unsigned short f2bf(float f) {
    unsigned int u = __builtin_bit_cast(unsigned int, f);
    u += 0x7FFFu + ((u >> 16) & 1u);
    return (unsigned short)(u >> 16);
}
__device__ __forceinline__ unsigned int pk2(float a, float b) {
    return (unsigned int)f2bf(a) | ((unsigned int)f2bf(b) << 16);
}

// ---------------- prep: f32 cache/new -> bf16 fragment-ordered ws ----------------
__global__ __launch_bounds__(256)
void prep(const float* __restrict__ ks, const float* __restrict__ vs,
          const float* __restrict__ kc, const float* __restrict__ vc,
          const int* __restrict__ qlens, const int* __restrict__ clens,
          unsigned short* __restrict__ Kws, unsigned short* __restrict__ Vws)
{
    const int tile = blockIdx.x, h = blockIdx.y, b = blockIdx.z;
    const int qlen = qlens[b], clen = clens[b];
    if (tile * KT >= clen + qlen) return;
    const int tid = threadIdx.x;
    unsigned short* kout = Kws + (((size_t)b * HH + h) * NTILES + tile) * TILE_ELEMS;
    unsigned short* vout = Vws + (((size_t)b * HH + h) * NTILES + tile) * TILE_ELEMS;

    // K fragments: off = half*2048 + c*512 + key15*32 + g*8 + e
    #pragma unroll
    for (int half = 0; half < 2; ++half) {
        int idx = tid * 8;
        int c = (idx >> 9) & 3, key15 = (idx >> 5) & 15, g = (idx >> 3) & 3;
        int key = tile * KT + half * 16 + key15;
        const float* src;
        if (key < clen) {
            src = kc + (((size_t)b * SS + key) * HH + h) * DD;
        } else {
            int i2 = key - clen; if (i2 > QQ - 1) i2 = QQ - 1;
            src = ks + (((size_t)b * QQ + i2) * HH + h) * DD;
        }
        int d0 = c * 32 + g * 8;
        f32x4 a0 = *(const f32x4*)&src[d0];
        f32x4 a1 = *(const f32x4*)&src[d0 + 4];
        u16x8 w;
        w[0] = f2bf(a0[0]); w[1] = f2bf(a0[1]); w[2] = f2bf(a0[2]); w[3] = f2bf(a0[3]);
        w[4] = f2bf(a1[0]); w[5] = f2bf(a1[1]); w[6] = f2bf(a1[2]); w[7] = f2bf(a1[3]);
        *(u16x8*)&kout[half * 2048 + idx] = w;
    }
    // V^T fragments: off = n*512 + lc*32 + g*8 + e  = V[key=g*8+e][d=n*16+lc]
    #pragma unroll
    for (int it = 0; it < 2; ++it) {
        int idx = it * 2048 + tid * 8;
        int n = (idx >> 9) & 7, lc = (idx >> 5) & 15, g = (idx >> 3) & 3;
        int d = n * 16 + lc;
        u16x8 w;
        #pragma unroll
        for (int e = 0; e < 8; ++e) {
            int key = tile * KT + g * 8 + e;
            const float* src;
            if (key < clen) {
                src = vc + (((size_t)b * SS + key) * HH + h) * DD;
            } else {
                int i2 = key - clen; if (i2 > QQ - 1) i2 = QQ - 1;
                src = vs + (((size_t)b * QQ + i2) * HH + h) * DD;
            }
            w[e] = f2bf(src[d]);
        }
        *(u16x8*)&vout[idx] = w;
    }
}

// ---------------- hot kernel: zero LDS, lane-local softmax ----------------
__global__ __launch_bounds__(256)
void segattn_fast(const float* __restrict__ qs, const int* __restrict__ qlens,
                  const int* __restrict__ clens,
                  const unsigned short* __restrict__ Kws,
                  const unsigned short* __restrict__ Vws,
                  float* __restrict__ out)
{
    const int id = blockIdx.x;
    int qt = id & 15;
    const int h = (id >> 4) & 31, b = id >> 9;
    qt = (qt + h) & 15;                 // decorrelate work level from XCD residue
    const int tid = threadIdx.x, wave = tid >> 6, lane = tid & 63;
    const int g = lane >> 4, lc = lane & 15;
    const int qlen = qlens[b], clen = clens[b];
    const int q0 = qt * QT;

    if (q0 >= qlen) {                   // fully padded tile -> zeros
        f32x4 z = {0.f, 0.f, 0.f, 0.f};
        #pragma unroll
        for (int i2 = 0; i2 < 8; ++i2) {
            int f = tid + i2 * 256;
            int r = f >> 5, d4 = f & 31;
            *(f32x4*)&out[(((size_t)b * QQ + q0 + r) * HH + h) * DD + d4 * 4] = z;
        }
        return;
    }

    // ---- Q fragment (B-role), pre-scaled, q-row = lc
    const float psc = 0.08838834764831845f * 1.4426950408889634f;
    const int q = q0 + wave * 16 + lc;
    const float* qp = qs + (((size_t)b * QQ + q) * HH + h) * DD;
    short8 qf[4];
    #pragma unroll
    for (int c = 0; c < 4; ++c) {
        f32x4 a0 = *(const f32x4*)&qp[c * 32 + g * 8];
        f32x4 a1 = *(const f32x4*)&qp[c * 32 + g * 8 + 4];
        short8 t;
        t[0] = (short)f2bf(a0[0] * psc); t[1] = (short)f2bf(a0[1] * psc);
        t[2] = (short)f2bf(a0[2] * psc); t[3] = (short)f2bf(a0[3] * psc);
        t[4] = (short)f2bf(a1[0] * psc); t[5] = (short)f2bf(a1[1] * psc);
        t[6] = (short)f2bf(a1[2] * psc); t[7] = (short)f2bf(a1[3] * psc);
        qf[c] = t;
    }

    const int lim_l = (q < qlen) ? (clen + q + 1) : 0;   // per-lane causal limit
    float m_ = -3e38f, l_ = 0.f;
    f32x4 o[8];
    #pragma unroll
    for (int n = 0; n < 8; ++n) o[n] = (f32x4){0.f, 0.f, 0.f, 0.f};

    // bpermute byte addrs: even/odd source g within this lane's lc
    const int srcE = ((g & 1) << 1);                 // 0 or 2
    const int addrE = ((srcE << 4) + lc) << 2;
    const int addrO = addrE + 64;                    // +16 lanes
    const bool useB = (g >= 2);                      // upper half keys come from sc1 packs

    const int kmax = clen + min(q0 + QT, qlen);
    const int nt = (kmax + KT - 1) / KT;
    const unsigned short* Kb = Kws + ((size_t)(b * HH + h)) * NTILES * TILE_ELEMS;
    const unsigned short* Vb = Vws + ((size_t)(b * HH + h)) * NTILES * TILE_ELEMS;
    const int fo = lc * 32 + g * 8;

    // preload K fragments for tile 0
    short8 kf[8];
    #pragma unroll
    for (int c = 0; c < 4; ++c) {
        kf[c]     = *(const short8*)&Kb[c * 512 + fo];
        kf[4 + c] = *(const short8*)&Kb[2048 + c * 512 + fo];
    }

    for (int t = 0; t < nt; ++t) {
        const int pbase = t * KT;
        // prefetch next tile's K fragments
        const int tn = (t + 1 < nt) ? t + 1 : nt - 1;
        const unsigned short* ktn = Kb + (size_t)tn * TILE_ELEMS;
        short8 kn[8];
        #pragma unroll
        for (int c = 0; c < 4; ++c) {
            kn[c]     = *(const short8*)&ktn[c * 512 + fo];
            kn[4 + c] = *(const short8*)&ktn[2048 + c * 512 + fo];
        }
        // early V loads for current tile
        const unsigned short* vt_ = Vb + (size_t)t * TILE_ELEMS;
        short8 vf[8];
        #pragma unroll
        for (int n = 0; n < 8; ++n) vf[n] = *(const short8*)&vt_[n * 512 + fo];

        // QK^T swapped: D[row=k][col=q]; lane holds k = {4g..4g+3} u {16+4g..}
        f32x4 s0 = {0.f, 0.f, 0.f, 0.f}, s1 = {0.f, 0.f, 0.f, 0.f};
        #pragma unroll
        for (int c = 0; c < 4; ++c) {
            s0 = __builtin_amdgcn_mfma_f32_16x16x32_bf16(kf[c],     qf[c], s0, 0, 0, 0);
            s1 = __builtin_amdgcn_mfma_f32_16x16x32_bf16(kf[4 + c], qf[c], s1, 0, 0, 0);
        }

        // mask
        const int kg0 = pbase + g * 4, kg1 = kg0 + 16;
        #pragma unroll
        for (int r = 0; r < 4; ++r) {
            if (kg0 + r >= lim_l) s0[r] = -3e38f;
            if (kg1 + r >= lim_l) s1[r] = -3e38f;
        }

        // lane-local max + 2-hop cross-group reduce
        float pm = fmaxf(fmaxf(fmaxf(s0[0], s0[1]), fmaxf(s0[2], s0[3])),
                         fmaxf(fmaxf(s1[0], s1[1]), fmaxf(s1[2], s1[3])));
        pm = fmaxf(pm, __shfl_xor(pm, 16));
        pm = fmaxf(pm, __shfl_xor(pm, 32));
        const float mn = fmaxf(m_, pm);
        const float alpha = __builtin_amdgcn_exp2f(m_ - mn);
        float p[8];
        #pragma unroll
        for (int r = 0; r < 4; ++r) {
            p[r]     = __builtin_amdgcn_exp2f(s0[r] - mn);
            p[4 + r] = __builtin_amdgcn_exp2f(s1[r] - mn);
        }
        float ps = ((p[0] + p[1]) + (p[2] + p[3])) + ((p[4] + p[5]) + (p[6] + p[7]));
        ps += __shfl_xor(ps, 16);
        ps += __shfl_xor(ps, 32);
        l_ = l_ * alpha + ps;
        m_ = mn;

        // pack P and relayout to B-fragment via 8 bpermutes (no LDS)
        const int A0 = (int)pk2(p[0], p[1]), A1 = (int)pk2(p[2], p[3]);
        const int B0 = (int)pk2(p[4], p[5]), B1 = (int)pk2(p[6], p[7]);
        int dw0a = __builtin_amdgcn_ds_bpermute(addrE, A0);
        int dw0b = __builtin_amdgcn_ds_bpermute(addrE, B0);
        int dw1a = __builtin_amdgcn_ds_bpermute(addrE, A1);
        int dw1b = __builtin_amdgcn_ds_bpermute(addrE, B1);
        int dw2a = __builtin_amdgcn_ds_bpermute(addrO, A0);
        int dw2b = __builtin_amdgcn_ds_bpermute(addrO, B0);
        int dw3a = __builtin_amdgcn_ds_bpermute(addrO, A1);
        int dw3b = __builtin_amdgcn_ds_bpermute(addrO, B1);
        u32x4 pbw;
        pbw[0] = (unsigned int)(useB ? dw0b : dw0a);
        pbw[1] = (unsigned int)(useB ? dw1b : dw1a);
        pbw[2] = (unsigned int)(useB ? dw2b : dw2a);
        pbw[3] = (unsigned int)(useB ? dw3b : dw3a);
        const short8 pb = __builtin_bit_cast(short8, pbw);

        // rescale O, then PV: o[n] = V^T_n · P  (D[row=d_local][col=q])
        #pragma unroll
        for (int n = 0; n < 8; ++n) {
            o[n][0] *= alpha; o[n][1] *= alpha; o[n][2] *= alpha; o[n][3] *= alpha;
        }
        #pragma unroll
        for (int n = 0; n < 8; ++n)
            o[n] = __builtin_amdgcn_mfma_f32_16x16x32_bf16(vf[n], pb, o[n], 0, 0, 0);

        #pragma unroll
        for (int j = 0; j < 8; ++j) kf[j] = kn[j];
    }

    // ---- epilogue: lane owns q = lc row, d = 16n + 4g + r -> float4 stores
    const bool val = (q < qlen);
    const float inv = val ? (1.0f / l_) : 0.f;
    float* op = out + (((size_t)b * QQ + q) * HH + h) * DD + g * 4;
    #pragma unroll
    for (int n = 0; n < 8; ++n) {
        f32x4 w;
        w[0] = o[n][0] * inv; w[1] = o[n][1] * inv;
        w[2] = o[n][2] * inv; w[3] = o[n][3] * inv;
        *(f32x4*)&op[n * 16] = w;
    }
}

// ---------------- R1 fallback (proven) if ws too small ----------------
__global__ __launch_bounds__(256)
void segattn(const float* __restrict__ qs, const float* __restrict__ ks,
             const float* __restrict__ vs, const float* __restrict__ kc,
             const float* __restrict__ vc, const int* __restrict__ qlens,
             const int* __restrict__ clens, float* __restrict__ out)
{
    const int qt = blockIdx.x, h = blockIdx.y, b = blockIdx.z;
    const int tid = threadIdx.x, wave = tid >> 6, lane = tid & 63;
    const int g = lane >> 4, lc = lane & 15;
    const int qlen = qlens[b], clen = clens[b];
    const int q0 = qt * QT;
    if (q0 >= qlen) {
        f32x4 z = {0.f, 0.f, 0.f, 0.f};
        #pragma unroll
        for (int i2 = 0; i2 < 8; ++i2) {
            int f = tid + i2 * 256;
            int r = f >> 5, d4 = f & 31;
            *(f32x4*)&out[(((size_t)b * QQ + q0 + r) * HH + h) * DD + d4 * 4] = z;
        }
        return;
    }
    alignas(16) __shared__ unsigned short Kl[KT * DD];
    alignas(16) __shared__ unsigned short Vl[DD * 40];
    alignas(16) __shared__ unsigned short Pl[4][16][40];
    const float psc = 0.08838834764831845f * 1.4426950408889634f;
    const int qrow = q0 + wave * 16 + lc;
    const float* qp = qs + (((size_t)b * QQ + qrow) * HH + h) * DD;
    short8 qf[4];
    #pragma unroll
    for (int c = 0; c < 4; ++c) {
        f32x4 a0 = *(const f32x4*)&qp[c * 32 + g * 8];
        f32x4 a1 = *(const f32x4*)&qp[c * 32 + g * 8 + 4];
        short8 t;
        t[0] = (short)f2bf(a0[0] * psc); t[1] = (short)f2bf(a0[1] * psc);
        t[2] = (short)f2bf(a0[2] * psc); t[3] = (short)f2bf(a0[3] * psc);
        t[4] = (short)f2bf(a1[0] * psc); t[5] = (short)f2bf(a1[1] * psc);
        t[6] = (short)f2bf(a1[2] * psc); t[7] = (short)f2bf(a1[3] * psc);
        qf[c] = t;
    }
    f32x4 o[8];
    #pragma unroll
    for (int n = 0; n < 8; ++n) o[n] = (f32x4){0.f, 0.f, 0.f, 0.f};
    float m_[4] = {-3e38f, -3e38f, -3e38f, -3e38f};
    float l_[4] = {0.f, 0.f, 0.f, 0.f};
    int lim[4];
    #pragma unroll
    for (int qq = 0; qq < 4; ++qq) {
        int i = q0 + wave * 16 + g * 4 + qq;
        lim[qq] = (i < qlen) ? (clen + i + 1) : 0;
    }
    const int kmax = clen + min(q0 + QT, qlen);
    const int nt = (kmax + KT - 1) / KT;
    for (int t = 0; t < nt; ++t) {
        const int pbase = t * KT;
        __syncthreads();
        #pragma unroll
        for (int it = 0; it < 4; ++it) {
            int f = tid + it * 256;
            int key = f >> 5, d4 = f & 31;
            int p = pbase + key;
            const float *srck, *srcv;
            if (p < clen) {
                size_t off = (((size_t)b * SS + p) * HH + h) * DD + d4 * 4;
                srck = kc + off; srcv = vc + off;
            } else {
                int idx = p - clen; if (idx > QQ - 1) idx = QQ - 1;
                size_t off = (((size_t)b * QQ + idx) * HH + h) * DD + d4 * 4;
                srck = ks + off; srcv = vs + off;
            }
            f32x4 kv = *(const f32x4*)srck;
            f32x4 vv = *(const f32x4*)srcv;
            int ei = (key * DD + d4 * 4) ^ ((key & 7) << 3);
            typedef __attribute__((ext_vector_type(4))) unsigned short u16x4;
            u16x4 kb4 = {f2bf(kv[0]), f2bf(kv[1]), f2bf(kv[2]), f2bf(kv[3])};
            *(u16x4*)&Kl[ei] = kb4;
            int d0 = d4 * 4;
            Vl[(d0 + 0) * 40 + key] = f2bf(vv[0]);
            Vl[(d0 + 1) * 40 + key] = f2bf(vv[1]);
            Vl[(d0 + 2) * 40 + key] = f2bf(vv[2]);
            Vl[(d0 + 3) * 40 + key] = f2bf(vv[3]);
        }
        __syncthreads();
        f32x4 sc0 = {0.f, 0.f, 0.f, 0.f}, sc1 = {0.f, 0.f, 0.f, 0.f};
        #pragma unroll
        for (int c = 0; c < 4; ++c) {
            int i0 = (lc * DD + c * 32 + g * 8) ^ ((lc & 7) << 3);
            int i1 = ((16 + lc) * DD + c * 32 + g * 8) ^ (((16 + lc) & 7) << 3);
            short8 k0 = *(const short8*)&Kl[i0];
            short8 k1 = *(const short8*)&Kl[i1];
            sc0 = __builtin_amdgcn_mfma_f32_16x16x32_bf16(qf[c], k0, sc0, 0, 0, 0);
            sc1 = __builtin_amdgcn_mfma_f32_16x16x32_bf16(qf[c], k1, sc1, 0, 0, 0);
        }
        float pr0[4], pr1[4];
        #pragma unroll
        for (int qq = 0; qq < 4; ++qq) {
            float s0 = sc0[qq], s1 = sc1[qq];
            if (pbase + lc >= lim[qq])      s0 = -3e38f;
            if (pbase + 16 + lc >= lim[qq]) s1 = -3e38f;
            float pm = fmaxf(s0, s1);
            #pragma unroll
            for (int d2 = 1; d2 < 16; d2 <<= 1) pm = fmaxf(pm, __shfl_xor(pm, d2));
            float mn = fmaxf(m_[qq], pm);
            float alpha = exp2f(m_[qq] - mn);
            float p0 = exp2f(s0 - mn), p1 = exp2f(s1 - mn);
            float rs = p0 + p1;
            #pragma unroll
            for (int d2 = 1; d2 < 16; d2 <<= 1) rs += __shfl_xor(rs, d2);
            l_[qq] = l_[qq] * alpha + rs;
            m_[qq] = mn;
            pr0[qq] = p0; pr1[qq] = p1;
            #pragma unroll
            for (int n = 0; n < 8; ++n) o[n][qq] *= alpha;
        }
        #pragma unroll
        for (int qq = 0; qq < 4; ++qq) {
            Pl[wave][g * 4 + qq][lc]      = f2bf(pr0[qq]);
            Pl[wave][g * 4 + qq][16 + lc] = f2bf(pr1[qq]);
        }
        short8 pf = *(const short8*)&Pl[wave][lc][g * 8];
        #pragma unroll
        for (int n = 0; n < 8; ++n) {
            short8 vf = *(const short8*)&Vl[(n * 16 + lc) * 40 + g * 8];
            o[n] = __builtin_amdgcn_mfma_f32_16x16x32_bf16(pf, vf, o[n], 0, 0, 0);
        }
    }
    #pragma unroll
    for (int qq = 0; qq < 4; ++qq) {
        int i = q0 + wave * 16 + g * 4 + qq;
        bool val = (i < qlen);
        float inv = val ? (1.0f / l_[qq]) : 0.f;
        size_t ob = (((size_t)b * QQ + i) * HH + h) * DD + lc;
        #pragma unroll
        for (int n = 0; n < 8; ++n)
            out[ob + (size_t)n * 16] = val ? o[n][qq] * inv : 0.f;
    }
}

extern "C" void kernel_launch(void* const* d_in, const int* in_sizes, int n_in,
                              void* d_out, int out_size, void* d_ws, size_t ws_size,
                              hipStream_t stream) {
    const float* qs = (const float*)d_in[0];
    const float* ks = (const float*)d_in[1];
    const float* vs = (const float*)d_in[2];
    const float* kc = (const float*)d_in[3];
    const float* vc = (const float*)d_in[4];
    const int* ql = (const int*)d_in[5];
    const int* cl = (const int*)d_in[6];
    float* o = (float*)d_out;

    const size_t kv_elems = (size_t)BB * HH * NTILES * TILE_ELEMS;
    const size_t need = kv_elems * 2 * sizeof(unsigned short);   // 128 MiB

    if (ws_size >= need) {
        unsigned short* Kws = (unsigned short*)d_ws;
        unsigned short* Vws = Kws + kv_elems;
        dim3 pgrid(NTILES, HH, BB), pblk(256, 1, 1);
        hipLaunchKernelGGL(prep, pgrid, pblk, 0, stream, ks, vs, kc, vc, ql, cl, Kws, Vws);
        dim3 grid(2048, 1, 1), blk(256, 1, 1);
        hipLaunchKernelGGL(segattn_fast, grid, blk, 0, stream, qs, ql, cl, Kws, Vws, o);
    } else {
        dim3 grid(QQ / QT, HH, BB), blk(256, 1, 1);
        hipLaunchKernelGGL(segattn, grid, blk, 0, stream, qs, ks, vs, kc, vc, ql, cl, o);
    }
}